// Round 9
// baseline (196.237 us; speedup 1.0000x reference)
//
#include <hip/hip_runtime.h>
#include <hip/hip_bf16.h>
#include <math.h>

// Problem constants (SchNet reference)
#define NATOMS 16384
#define NMOL   512
#define APM    32
#define GDIM   50
#define KTAB   2048   // filter lookup-table knots over d in [0,6]
#define MAXEPM 992    // max edges per molecule = 32*31

#define STRH 132      // s_h row stride (floats), 528B
#define STRA 136      // s_agg / s_t row stride (ushorts), 272B

typedef __attribute__((ext_vector_type(8))) short   short8;   // 8 bf16 (A/B frag)
typedef __attribute__((ext_vector_type(4))) float   floatx4;  // C/D frag

// fast shifted softplus: log(1+exp(x)) - log2, via HW v_exp_f32/v_log_f32
__device__ __forceinline__ float ssp(float x) {
    float e = __expf(-fabsf(x));
    return fmaxf(x, 0.0f) + __logf(1.0f + e) - 0.69314718055994531f;
}

__device__ __forceinline__ unsigned short f2bf(float x) {
    union { float f; unsigned int u; } v; v.f = x;
    unsigned int lsb = (v.u >> 16) & 1u;
    v.u += 0x7fffu + lsb;
    return (unsigned short)(v.u >> 16);
}

__device__ __forceinline__ unsigned int pk2bf(float a, float b) {
    __hip_bfloat162 h = __float22bfloat162_rn(make_float2(a, b));
    unsigned int u;
    __builtin_memcpy(&u, &h, 4);
    return u;
}

// ---------------------------------------------------------------------------
// Merged setup: per-edge packed meta {knot<<5 | dst&31, frac}, rowptr,
// bf16 B-frag weight transposes (9x128x128 + out1 64x128). One dispatch.
// ---------------------------------------------------------------------------
__global__ __launch_bounds__(256) void setup_kernel(
    const float* __restrict__ pos, const int* __restrict__ eidx, int E,
    int* __restrict__ rowptr,
    const float* __restrict__ cf1, const float* __restrict__ cf2,
    const float* __restrict__ lin, const float* __restrict__ out1,
    unsigned short* __restrict__ Wtall, uint2* __restrict__ meta)
{
    int idx = blockIdx.x * 256 + threadIdx.x;
    if (idx < E) {
        int s = eidx[idx], t = eidx[E + idx];
        float dx = pos[3 * s]     - pos[3 * t];
        float dy = pos[3 * s + 1] - pos[3 * t + 1];
        float dz = pos[3 * s + 2] - pos[3 * t + 2];
        float d  = sqrtf(dx * dx + dy * dy + dz * dz);
        float u  = d * (float)(KTAB - 1) / 6.0f;
        int i = min((int)u, KTAB - 2);
        float frac = u - (float)i;
        meta[idx] = make_uint2(((unsigned)i << 5) | (unsigned)(t & 31),
                               __float_as_uint(frac));
    } else if (idx < E + NATOMS + 1) {
        int a = idx - E;
        int lo = 0, hi = E;
        while (lo < hi) { int mid = (lo + hi) >> 1; if (eidx[mid] < a) lo = mid + 1; else hi = mid; }
        rowptr[a] = lo;
    } else if (idx < E + NATOMS + 1 + 9 * 16384 + 64 * 128) {
        int r = idx - (E + NATOMS + 1);
        if (r < 9 * 16384) {
            int wi = r >> 14, rem = r & 16383;
            int n = rem >> 7, k = rem & 127;
            int l = wi / 3, which = wi % 3;
            const float* src = (which == 0) ? cf1 : (which == 1) ? cf2 : lin;
            Wtall[r] = f2bf(src[(size_t)l * 16384 + k * 128 + n]);
        } else {
            int q = r - 9 * 16384;
            int n = q >> 7, k = q & 127;
            Wtall[r] = f2bf(out1[k * 64 + n]);
        }
    }
}

// ---------------------------------------------------------------------------
// Build filter table: T[l][k][f] = ((ssp(ea(d_k)@w1+b1)@w2)+b2)*cut(d_k), bf16
// ---------------------------------------------------------------------------
#define KW1 72
#define KW2 136

__global__ __launch_bounds__(256, 2) void build_table_kernel(
    const float* __restrict__ w1_, const float* __restrict__ b1_,
    const float* __restrict__ w2_, const float* __restrict__ b2_,
    unsigned short* __restrict__ T_)
{
    const int l = blockIdx.y;
    const float* w1 = w1_ + (size_t)l * GDIM * 128;
    const float* b1 = b1_ + (size_t)l * 128;
    const float* w2 = w2_ + (size_t)l * 128 * 128;
    const float* b2 = b2_ + (size_t)l * 128;
    unsigned short* T = T_ + (size_t)l * KTAB * 128;

    __shared__ unsigned short s_w1T[128 * KW1];
    __shared__ unsigned short s_w2T[128 * KW2];
    __shared__ unsigned short s_t[64 * KW2];

    const int tid = threadIdx.x;
    for (int i = tid; i < GDIM * 128; i += 256) {
        int g = i >> 7, f = i & 127;
        s_w1T[f * KW1 + g] = f2bf(w1[i]);
    }
    for (int i = tid; i < (64 - GDIM) * 128; i += 256) {
        int g = GDIM + (i >> 7), f = i & 127;
        s_w1T[f * KW1 + g] = 0;
    }
    for (int i = tid; i < 128 * 128; i += 256) {
        int k = i >> 7, n = i & 127;
        s_w2T[n * KW2 + k] = f2bf(w2[i]);
    }

    const int lane = tid & 63;
    const int w    = tid >> 6;
    const int l15  = lane & 15;
    const int quad = lane >> 4;

    float b1v[8], b2v[8];
    #pragma unroll
    for (int nt = 0; nt < 8; nt++) {
        b1v[nt] = b1[nt * 16 + l15];
        b2v[nt] = b2[nt * 16 + l15];
    }
    __syncthreads();

    const float hstep = 6.0f / (float)(KTAB - 1);
    const float step  = 6.0f / 49.0f;
    const float coeff = -0.5f / (step * step);
    const float pioc  = 3.14159265358979323846f / 6.0f;
    const int k0 = blockIdx.x * 64;
    const float dm = (float)(k0 + w * 16 + l15) * hstep;

    floatx4 acc1[8];
    #pragma unroll
    for (int nt = 0; nt < 8; nt++) acc1[nt] = (floatx4){0.f, 0.f, 0.f, 0.f};
    #pragma unroll
    for (int ks = 0; ks < 2; ks++) {
        unsigned int ap[4];
        #pragma unroll
        for (int jj = 0; jj < 4; jj++) {
            int g0 = ks * 32 + quad * 8 + 2 * jj;
            float d0 = dm - (float)g0 * step;
            float d1 = dm - (float)(g0 + 1) * step;
            float v0 = (g0 < GDIM)     ? __expf(coeff * d0 * d0) : 0.0f;
            float v1 = (g0 + 1 < GDIM) ? __expf(coeff * d1 * d1) : 0.0f;
            ap[jj] = pk2bf(v0, v1);
        }
        short8 af;
        __builtin_memcpy(&af, ap, 16);
        #pragma unroll
        for (int nt = 0; nt < 8; nt++) {
            short8 bfg = *(const short8*)&s_w1T[(nt * 16 + l15) * KW1 + ks * 32 + quad * 8];
            acc1[nt] = __builtin_amdgcn_mfma_f32_16x16x32_bf16(af, bfg, acc1[nt], 0, 0, 0);
        }
    }
    #pragma unroll
    for (int nt = 0; nt < 8; nt++) {
        #pragma unroll
        for (int r = 0; r < 4; r++) {
            int row = w * 16 + quad * 4 + r;
            s_t[row * KW2 + nt * 16 + l15] = f2bf(ssp(acc1[nt][r] + b1v[nt]));
        }
    }
    // no barrier: wave reads only rows it wrote

    floatx4 acc2[8];
    #pragma unroll
    for (int nt = 0; nt < 8; nt++) acc2[nt] = (floatx4){0.f, 0.f, 0.f, 0.f};
    #pragma unroll
    for (int ks = 0; ks < 4; ks++) {
        short8 af = *(const short8*)&s_t[(w * 16 + l15) * KW2 + ks * 32 + quad * 8];
        #pragma unroll
        for (int nt = 0; nt < 8; nt++) {
            short8 bfg = *(const short8*)&s_w2T[(nt * 16 + l15) * KW2 + ks * 32 + quad * 8];
            acc2[nt] = __builtin_amdgcn_mfma_f32_16x16x32_bf16(af, bfg, acc2[nt], 0, 0, 0);
        }
    }

    #pragma unroll
    for (int nt = 0; nt < 8; nt++) {
        #pragma unroll
        for (int r = 0; r < 4; r++) {
            int row = w * 16 + quad * 4 + r;
            float d = (float)(k0 + row) * hstep;
            float cut = 0.5f * (__cosf(d * pioc) + 1.0f);
            T[(size_t)(k0 + row) * 128 + nt * 16 + l15] = f2bf((acc2[nt][r] + b2v[nt]) * cut);
        }
    }
}

// pack (w0, dw) knots: Tp[l][k][f] = T[k][f] | bf16(T[k+1][f]-T[k][f])<<16
__global__ __launch_bounds__(256) void pack_table_kernel(
    const unsigned short* __restrict__ T, unsigned int* __restrict__ Tp)
{
    int idx = blockIdx.x * 256 + threadIdx.x;    // over 3*KTAB*128
    int k = (idx >> 7) & (KTAB - 1);
    unsigned int w0 = T[idx];
    float w0f = __uint_as_float(w0 << 16);
    float w1f = (k == KTAB - 1) ? w0f
              : __uint_as_float((unsigned int)T[idx + 128] << 16);
    unsigned int dw = f2bf(w1f - w0f);
    Tp[idx] = w0 | (dw << 16);
}

// ---------------------------------------------------------------------------
// Fully-fused SchNet: one block = one molecule, 1024 threads = 16 waves
// (2 blocks/CU -> 32 waves/CU, the HW occupancy cap; LDS ~49KB/block,
// VGPR ~56 so nothing else limits). Wave w: GEMM tile rows (w&1)*16,
// cols (w>>1)*16; gather atoms w*2..w*2+2. Edge metadata staged in LDS;
// gather inner loop = one 8B global load (packed (w0,dw) lerp slice)
// per edge, 8-deep unrolled.
// ---------------------------------------------------------------------------
__global__ __launch_bounds__(1024) void fused_schnet_kernel(
    const int* __restrict__ z, const float* __restrict__ emb,
    const int* __restrict__ rowptr, const uint2* __restrict__ meta,
    const unsigned int* __restrict__ Tp,
    const unsigned short* __restrict__ Wtall,
    const float* __restrict__ cf2_b, const float* __restrict__ lin_b,
    const float* __restrict__ out1_b, const float* __restrict__ out2_w,
    const float* __restrict__ out2_b,
    float* __restrict__ out)
{
    __shared__ float s_h[32 * STRH];                 // 16.9 KB fp32 node state
    __shared__ float s_hx[32 * 128];                 // 16.4 KB (aliased by s_t)
    __shared__ unsigned short s_agg[32 * STRA];      //  8.7 KB
    __shared__ uint2 s_meta[MAXEPM];                 //  7.9 KB
    __shared__ float s_red;
    unsigned short* s_t = (unsigned short*)s_hx;     // [32][STRA] bf16 alias

    const int tid  = threadIdx.x;
    const int lane = tid & 63;
    const int w    = tid >> 6;          // wave 0..15
    const int l15  = lane & 15;
    const int quad = lane >> 4;
    const int r16  = (w & 1) * 16;      // GEMM row tile (2)
    const int c16  = (w >> 1) * 16;     // GEMM col tile (8)
    const int B0   = blockIdx.x * 32;   // molecule base atom

    // init h from embedding
    for (int i = tid; i < 32 * 128; i += 1024) {
        int row = i >> 7, col = i & 127;
        s_h[row * STRH + col] = emb[(size_t)z[B0 + row] * 128 + col];
    }
    if (tid == 0) s_red = 0.0f;

    // stage this molecule's edge metadata into LDS (layer-invariant)
    const int ebase = rowptr[B0];
    const int nE    = rowptr[B0 + 32] - ebase;
    for (int i = tid; i < nE; i += 1024) s_meta[i] = meta[ebase + i];

    // local row pointers for this wave's 2 atoms (3 bounds in lanes 0..2)
    const int rp = rowptr[B0 + w * 2 + min(lane, 2)] - ebase;

    const unsigned short* WtO = Wtall + 9 * 16384;   // out1^T

    for (int l = 0; l < 3; l++) {
        const unsigned short* W1 = Wtall + (size_t)(l * 3 + 0) * 16384;
        const unsigned short* W2 = Wtall + (size_t)(l * 3 + 1) * 16384;
        const unsigned short* W3 = Wtall + (size_t)(l * 3 + 2) * 16384;
        const unsigned int* Tpl  = Tp + (size_t)l * KTAB * 128;

        __syncthreads();   // h ready (also covers meta staging at l=0)

        // ---- GEMM1: hx = h @ cf1 (16x16 tile per wave) ----
        floatx4 acc = (floatx4){0.f, 0.f, 0.f, 0.f};
        #pragma unroll
        for (int ks = 0; ks < 4; ks++) {
            const float* hp = &s_h[(r16 + l15) * STRH + ks * 32 + quad * 8];
            float4 xa = *(const float4*)hp;
            float4 xb = *(const float4*)(hp + 4);
            unsigned int ap[4];
            ap[0] = pk2bf(xa.x, xa.y); ap[1] = pk2bf(xa.z, xa.w);
            ap[2] = pk2bf(xb.x, xb.y); ap[3] = pk2bf(xb.z, xb.w);
            short8 af;
            __builtin_memcpy(&af, ap, 16);
            short8 bfg = *(const short8*)&W1[(size_t)(c16 + l15) * 128 + ks * 32 + quad * 8];
            acc = __builtin_amdgcn_mfma_f32_16x16x32_bf16(af, bfg, acc, 0, 0, 0);
        }
        #pragma unroll
        for (int r = 0; r < 4; r++)
            s_hx[(r16 + quad * 4 + r) * 128 + c16 + l15] = acc[r];

        __syncthreads();   // hx complete before gather reads

        // ---- gather + lerp (wave per atom-pair) ----
        for (int al = 0; al < 2; al++) {
            const int e0 = __shfl(rp, al);
            const int e1 = __shfl(rp, al + 1);
            float ax[8], ay[8];
            #pragma unroll
            for (int j = 0; j < 8; j++) { ax[j] = 0.f; ay[j] = 0.f; }
            int e = e0;
            for (; e + 7 < e1; e += 8) {
                #pragma unroll
                for (int j = 0; j < 8; j++) {
                    uint2 q = s_meta[e + j];
                    int tl   = q.x & 31;
                    int knot = q.x >> 5;
                    uint2 tp = *(const uint2*)&Tpl[(size_t)knot * 128 + 2 * lane];
                    float2 hv = *(const float2*)&s_hx[tl * 128 + 2 * lane];
                    float fr = __uint_as_float(q.y);
                    float wx = fmaf(fr, __uint_as_float(tp.x & 0xffff0000u),
                                    __uint_as_float(tp.x << 16));
                    float wy = fmaf(fr, __uint_as_float(tp.y & 0xffff0000u),
                                    __uint_as_float(tp.y << 16));
                    ax[j] = fmaf(hv.x, wx, ax[j]);
                    ay[j] = fmaf(hv.y, wy, ay[j]);
                }
            }
            for (; e < e1; e++) {
                int j = (e - e0) & 7;
                uint2 q = s_meta[e];
                int tl   = q.x & 31;
                int knot = q.x >> 5;
                uint2 tp = *(const uint2*)&Tpl[(size_t)knot * 128 + 2 * lane];
                float2 hv = *(const float2*)&s_hx[tl * 128 + 2 * lane];
                float fr = __uint_as_float(q.y);
                float wx = fmaf(fr, __uint_as_float(tp.x & 0xffff0000u),
                                __uint_as_float(tp.x << 16));
                float wy = fmaf(fr, __uint_as_float(tp.y & 0xffff0000u),
                                __uint_as_float(tp.y << 16));
                ax[j] = fmaf(hv.x, wx, ax[j]);
                ay[j] = fmaf(hv.y, wy, ay[j]);
            }
            float sx = ((ax[0] + ax[1]) + (ax[2] + ax[3])) + ((ax[4] + ax[5]) + (ax[6] + ax[7]));
            float sy = ((ay[0] + ay[1]) + (ay[2] + ay[3])) + ((ay[4] + ay[5]) + (ay[6] + ay[7]));
            *(unsigned int*)&s_agg[(w * 2 + al) * STRA + 2 * lane] = pk2bf(sx, sy);
        }

        __syncthreads();   // agg complete; s_hx reads done (s_t alias safe)

        // ---- GEMM2: t = ssp(agg @ cf2 + b) ----
        const float bva = cf2_b[l * 128 + c16 + l15];
        const float bvb = lin_b[l * 128 + c16 + l15];
        acc = (floatx4){0.f, 0.f, 0.f, 0.f};
        #pragma unroll
        for (int ks = 0; ks < 4; ks++) {
            short8 af = *(const short8*)&s_agg[(r16 + l15) * STRA + ks * 32 + quad * 8];
            short8 bfg = *(const short8*)&W2[(size_t)(c16 + l15) * 128 + ks * 32 + quad * 8];
            acc = __builtin_amdgcn_mfma_f32_16x16x32_bf16(af, bfg, acc, 0, 0, 0);
        }
        #pragma unroll
        for (int r = 0; r < 4; r++) {
            int row = r16 + quad * 4 + r;
            s_t[row * STRA + c16 + l15] = f2bf(ssp(acc[r] + bva));
        }

        __syncthreads();   // t complete (cross-wave cols needed by GEMM3)

        // ---- GEMM3: h += t @ lin + b ----
        acc = (floatx4){0.f, 0.f, 0.f, 0.f};
        #pragma unroll
        for (int ks = 0; ks < 4; ks++) {
            short8 af = *(const short8*)&s_t[(r16 + l15) * STRA + ks * 32 + quad * 8];
            short8 bfg = *(const short8*)&W3[(size_t)(c16 + l15) * 128 + ks * 32 + quad * 8];
            acc = __builtin_amdgcn_mfma_f32_16x16x32_bf16(af, bfg, acc, 0, 0, 0);
        }
        #pragma unroll
        for (int r = 0; r < 4; r++) {
            int row = r16 + quad * 4 + r;
            s_h[row * STRH + c16 + l15] += acc[r] + bvb;
        }
        // loop-top __syncthreads covers h
    }

    __syncthreads();

    // ---- head: out = sum_a ssp(h@out1 + b1)@out2 + 32*b2 (waves 0..7) ----
    if (w < 8) {
        floatx4 ha = (floatx4){0.f, 0.f, 0.f, 0.f};
        #pragma unroll
        for (int ks = 0; ks < 4; ks++) {
            const float* hp = &s_h[(r16 + l15) * STRH + ks * 32 + quad * 8];
            float4 xa = *(const float4*)hp;
            float4 xb = *(const float4*)(hp + 4);
            unsigned int ap[4];
            ap[0] = pk2bf(xa.x, xa.y); ap[1] = pk2bf(xa.z, xa.w);
            ap[2] = pk2bf(xb.x, xb.y); ap[3] = pk2bf(xb.z, xb.w);
            short8 af;
            __builtin_memcpy(&af, ap, 16);
            short8 bfg = *(const short8*)&WtO[(size_t)(c16 + l15) * 128 + ks * 32 + quad * 8];
            ha = __builtin_amdgcn_mfma_f32_16x16x32_bf16(af, bfg, ha, 0, 0, 0);
        }
        float part = 0.0f;
        float b1o = out1_b[c16 + l15];
        float o2  = out2_w[c16 + l15];
        #pragma unroll
        for (int r = 0; r < 4; r++)
            part += ssp(ha[r] + b1o) * o2;
        #pragma unroll
        for (int off = 32; off > 0; off >>= 1) part += __shfl_down(part, off);
        if (lane == 0) atomicAdd(&s_red, part);
    }
    __syncthreads();
    if (tid == 0) out[blockIdx.x] = s_red + 32.0f * out2_b[0];
}

extern "C" void kernel_launch(void* const* d_in, const int* in_sizes, int n_in,
                              void* d_out, int out_size, void* d_ws, size_t ws_size,
                              hipStream_t stream)
{
    const int*   z      = (const int*)d_in[0];
    const float* pos    = (const float*)d_in[1];
    const int*   eidx   = (const int*)d_in[3];
    const float* emb    = (const float*)d_in[4];
    const float* mlp_w1 = (const float*)d_in[5];
    const float* mlp_b1 = (const float*)d_in[6];
    const float* mlp_w2 = (const float*)d_in[7];
    const float* mlp_b2 = (const float*)d_in[8];
    const float* cf1_w  = (const float*)d_in[9];
    const float* cf2_w  = (const float*)d_in[10];
    const float* cf2_b  = (const float*)d_in[11];
    const float* lin_w  = (const float*)d_in[12];
    const float* lin_b  = (const float*)d_in[13];
    const float* out1_w = (const float*)d_in[14];
    const float* out1_b = (const float*)d_in[15];
    const float* out2_w = (const float*)d_in[16];
    const float* out2_b = (const float*)d_in[17];
    const int E = in_sizes[3] / 2;

    // workspace carve-up (16B-aligned sections)
    char* p = (char*)d_ws;
    uint2* meta = (uint2*)p;                      p += ((size_t)E * 8 + 63) & ~63ULL;
    unsigned int* Tp = (unsigned int*)p;          p += (size_t)3 * KTAB * 128 * 4;
    int* rowptr = (int*)p;                        p += ((size_t)(NATOMS + 1) * 4 + 63) & ~63ULL;
    unsigned short* Ttab = (unsigned short*)p;    p += (size_t)3 * KTAB * 128 * 2;
    unsigned short* Wtall = (unsigned short*)p;   // 9*16384 + 64*128 ushorts

    const int setup_work = E + (NATOMS + 1) + 9 * 16384 + 64 * 128;
    setup_kernel<<<(setup_work + 255) / 256, 256, 0, stream>>>(
        pos, eidx, E, rowptr, cf1_w, cf2_w, lin_w, out1_w, Wtall, meta);
    build_table_kernel<<<dim3(KTAB / 64, 3), 256, 0, stream>>>(
        mlp_w1, mlp_b1, mlp_w2, mlp_b2, Ttab);
    pack_table_kernel<<<3 * KTAB * 128 / 256, 256, 0, stream>>>(Ttab, Tp);

    fused_schnet_kernel<<<NMOL, 1024, 0, stream>>>(
        z, emb, rowptr, meta, Tp, Wtall,
        cf2_b, lin_b, out1_b, out2_w, out2_b, (float*)d_out);
}